// Round 1
// baseline (22344.771 us; speedup 1.0000x reference)
//
#include <hip/hip_runtime.h>
#include <math.h>

#define BATCH 512
#define SEQL  128
#define PT    5
#define EH    256
#define ZS    128
#define DH    512
#define NM    20
#define NMAXT 256

__device__ __forceinline__ float sigf(float x) { return 1.0f / (1.0f + expf(-x)); }

#define FMA4(acc, av, wv)                                        \
    acc = fmaf(av.x, wv.x, acc); acc = fmaf(av.y, wv.y, acc);    \
    acc = fmaf(av.z, wv.z, acc); acc = fmaf(av.w, wv.w, acc);

// ---------------- encoder step: both directions, gates fused ----------------
// grid (8 batch-tiles of 64, 16 hid-tiles of 16, 2 dirs), block 256
__global__ __launch_bounds__(256) void enc_step(
    const float* __restrict__ s,
    const float* __restrict__ WihF, const float* __restrict__ WhhF, const float* __restrict__ bF,
    const float* __restrict__ WihB, const float* __restrict__ WhhB, const float* __restrict__ bB,
    const float* __restrict__ hfin, float* __restrict__ hfout, float* __restrict__ cf,
    const float* __restrict__ hbin, float* __restrict__ hbout, float* __restrict__ cb,
    int t)
{
    const int dir = blockIdx.z;
    const float* Wih  = dir ? WihB : WihF;
    const float* Whh  = dir ? WhhB : WhhF;
    const float* bias = dir ? bB   : bF;
    const float* hin  = dir ? hbin : hfin;
    float* hout       = dir ? hbout: hfout;
    float* c          = dir ? cb   : cf;
    const int ts = dir ? (SEQL - 1 - t) : t;
    const float* x = s + (size_t)ts * BATCH * PT;

    const int b0 = blockIdx.x * 64;
    const int n0 = blockIdx.y * 16;
    const int tid = threadIdx.x;
    const int col = tid & 15;   // hidden within tile
    const int bq  = tid >> 4;   // 0..15 -> 4 batches each

    __shared__ float A[64][68];        // h tile, pad->2-way max
    __shared__ float W[4][16][68];     // Whh tile per gate
    __shared__ float X[64][PT];

    if (tid < 64) {
        #pragma unroll
        for (int p = 0; p < PT; ++p) X[tid][p] = x[(b0 + tid) * PT + p];
    }

    float acc[4][4] = {};

    for (int k0 = 0; k0 < EH; k0 += 64) {
        __syncthreads();
        #pragma unroll
        for (int l = 0; l < 4; ++l) {
            int fi = tid + l * 256;
            int r = fi >> 4, c4 = fi & 15;
            *(float4*)&A[r][c4 * 4] =
                *(const float4*)&hin[(size_t)(b0 + r) * EH + k0 + c4 * 4];
        }
        #pragma unroll
        for (int l = 0; l < 4; ++l) {
            int fi = tid + l * 256;
            int g = fi >> 8, rr = (fi >> 4) & 15, c4 = fi & 15;
            *(float4*)&W[g][rr][c4 * 4] =
                *(const float4*)&Whh[(size_t)(g * EH + n0 + rr) * EH + k0 + c4 * 4];
        }
        __syncthreads();
        #pragma unroll
        for (int kk = 0; kk < 64; kk += 4) {
            float4 w0 = *(float4*)&W[0][col][kk];
            float4 w1 = *(float4*)&W[1][col][kk];
            float4 w2 = *(float4*)&W[2][col][kk];
            float4 w3 = *(float4*)&W[3][col][kk];
            #pragma unroll
            for (int j = 0; j < 4; ++j) {
                float4 av = *(float4*)&A[bq * 4 + j][kk];
                FMA4(acc[0][j], av, w0);
                FMA4(acc[1][j], av, w1);
                FMA4(acc[2][j], av, w2);
                FMA4(acc[3][j], av, w3);
            }
        }
    }

    const int hid = n0 + col;
    float w5[4][PT];
    #pragma unroll
    for (int g = 0; g < 4; ++g) {
        #pragma unroll
        for (int p = 0; p < PT; ++p) w5[g][p] = Wih[(g * EH + hid) * PT + p];
    }

    #pragma unroll
    for (int j = 0; j < 4; ++j) {
        const int br = bq * 4 + j;
        const int b  = b0 + br;
        float gv[4];
        #pragma unroll
        for (int g = 0; g < 4; ++g) {
            float v = acc[g][j] + bias[g * EH + hid];
            #pragma unroll
            for (int p = 0; p < PT; ++p) v = fmaf(X[br][p], w5[g][p], v);
            gv[g] = v;
        }
        const size_t idx = (size_t)b * EH + hid;
        const float iv = sigf(gv[0]);
        const float fv = sigf(gv[1]);
        const float gg = tanhf(gv[2]);
        const float ov = sigf(gv[3]);
        const float cv = fv * c[idx] + iv * gg;
        c[idx] = cv;
        hout[idx] = ov * tanhf(cv);
    }
}

// ---------------- latent: mu/sigma GEMMs + reparam, K=512 over [hf|hb] ----------------
// grid (8,4), block 256
__global__ __launch_bounds__(256) void latent_z(
    const float* __restrict__ hf, const float* __restrict__ hb,
    const float* __restrict__ Wmu, const float* __restrict__ bmu,
    const float* __restrict__ Wsig, const float* __restrict__ bsig,
    const float* __restrict__ zeps, float* __restrict__ z)
{
    const int b0 = blockIdx.x * 64;
    const int n0 = blockIdx.y * 32;
    const int tid = threadIdx.x;
    const int col = tid & 31;
    const int bq  = tid >> 5;   // 0..7 -> 8 batches each

    __shared__ float A[64][68];
    __shared__ float Wm[32][68];
    __shared__ float Ws[32][68];

    float am[8] = {}, as[8] = {};

    for (int k0 = 0; k0 < 2 * EH; k0 += 64) {
        const float* hsrc = (k0 < EH) ? hf : hb;
        const int kh = k0 & (EH - 1);
        __syncthreads();
        #pragma unroll
        for (int l = 0; l < 4; ++l) {
            int fi = tid + l * 256;
            int r = fi >> 4, c4 = fi & 15;
            *(float4*)&A[r][c4 * 4] =
                *(const float4*)&hsrc[(size_t)(b0 + r) * EH + kh + c4 * 4];
        }
        #pragma unroll
        for (int l = 0; l < 2; ++l) {
            int fi = tid + l * 256;
            int r = fi >> 4, c4 = fi & 15;
            *(float4*)&Wm[r][c4 * 4] =
                *(const float4*)&Wmu[(size_t)(n0 + r) * (2 * EH) + k0 + c4 * 4];
            *(float4*)&Ws[r][c4 * 4] =
                *(const float4*)&Wsig[(size_t)(n0 + r) * (2 * EH) + k0 + c4 * 4];
        }
        __syncthreads();
        #pragma unroll
        for (int kk = 0; kk < 64; kk += 4) {
            float4 wm = *(float4*)&Wm[col][kk];
            float4 ws = *(float4*)&Ws[col][kk];
            #pragma unroll
            for (int j = 0; j < 8; ++j) {
                float4 av = *(float4*)&A[bq * 8 + j][kk];
                FMA4(am[j], av, wm);
                FMA4(as[j], av, ws);
            }
        }
    }

    const int n = n0 + col;
    #pragma unroll
    for (int j = 0; j < 8; ++j) {
        const int b = b0 + bq * 8 + j;
        const float mu = am[j] + bmu[n];
        const float sg = expf(0.5f * (as[j] + bsig[n]));
        z[(size_t)b * ZS + n] = fmaf(sg, zeps[(size_t)b * ZS + n], mu);
    }
}

// ---------------- small generic GEMM: out = act(A @ W[:, koff:koff+K]^T + bias) ----------------
// grid (8, N/32), block 256. A is [512 x lda] (lda mult of 4), K mult of 64.
__global__ __launch_bounds__(256) void gemm_small(
    const float* __restrict__ A_, int lda,
    const float* __restrict__ Wt, int ldw, int koff,
    const float* __restrict__ bias,
    float* __restrict__ out, int ldo, int K, int act)
{
    const int b0 = blockIdx.x * 64;
    const int n0 = blockIdx.y * 32;
    const int tid = threadIdx.x;
    const int col = tid & 31;
    const int bq  = tid >> 5;

    __shared__ float A[64][68];
    __shared__ float W[32][68];

    float acc[8] = {};

    for (int k0 = 0; k0 < K; k0 += 64) {
        __syncthreads();
        #pragma unroll
        for (int l = 0; l < 4; ++l) {
            int fi = tid + l * 256;
            int r = fi >> 4, c4 = fi & 15;
            *(float4*)&A[r][c4 * 4] =
                *(const float4*)&A_[(size_t)(b0 + r) * lda + k0 + c4 * 4];
        }
        #pragma unroll
        for (int l = 0; l < 8; ++l) {   // scalar loads: W rows may be unaligned (ldw=133)
            int fi = tid + l * 256;
            int r = fi >> 6, cc2 = fi & 63;
            W[r][cc2] = Wt[(size_t)(n0 + r) * ldw + koff + k0 + cc2];
        }
        __syncthreads();
        #pragma unroll
        for (int kk = 0; kk < 64; kk += 4) {
            float4 wv = *(float4*)&W[col][kk];
            #pragma unroll
            for (int j = 0; j < 8; ++j) {
                float4 av = *(float4*)&A[bq * 8 + j][kk];
                FMA4(acc[j], av, wv);
            }
        }
    }

    const int n = n0 + col;
    const float bb = bias[n];
    #pragma unroll
    for (int j = 0; j < 8; ++j) {
        float v = acc[j] + bb;
        if (act) v = tanhf(v);
        out[(size_t)(b0 + bq * 8 + j) * ldo + n] = v;
    }
}

// ---------------- decoder LSTM step, gates fused ----------------
// grid (16 batch-tiles of 32, 16 hid-tiles of 32), block 256
__global__ __launch_bounds__(256) void dec_step(
    const float* __restrict__ hin, float* __restrict__ hout, float* __restrict__ cc,
    const float* __restrict__ Cz, const float* __restrict__ Whh,
    const float* __restrict__ Wih, const float* __restrict__ prevPt, int t)
{
    const int b0 = blockIdx.x * 32;
    const int n0 = blockIdx.y * 32;
    const int tid = threadIdx.x;
    const int col = tid & 31;
    const int bq  = tid >> 5;   // 0..7 -> 4 batches each

    __shared__ float A[32][68];
    __shared__ float W[4][32][68];
    __shared__ float Xp[32][PT];

    if (tid < 32) {
        if (t == 0) {
            Xp[tid][0] = 0.f; Xp[tid][1] = 0.f; Xp[tid][2] = 1.f; Xp[tid][3] = 0.f; Xp[tid][4] = 0.f;
        } else {
            #pragma unroll
            for (int p = 0; p < PT; ++p) Xp[tid][p] = prevPt[(b0 + tid) * PT + p];
        }
    }

    float acc[4][4] = {};

    for (int k0 = 0; k0 < DH; k0 += 64) {
        __syncthreads();
        #pragma unroll
        for (int l = 0; l < 2; ++l) {
            int fi = tid + l * 256;
            int r = fi >> 4, c4 = fi & 15;
            *(float4*)&A[r][c4 * 4] =
                *(const float4*)&hin[(size_t)(b0 + r) * DH + k0 + c4 * 4];
        }
        #pragma unroll
        for (int l = 0; l < 8; ++l) {
            int fi = tid + l * 256;
            int g = fi >> 9, rr = (fi >> 4) & 31, c4 = fi & 15;
            int sl = c4 ^ ((rr >> 3) & 3);   // xor-swizzle: conflict-free reads
            *(float4*)&W[g][rr][sl * 4] =
                *(const float4*)&Whh[(size_t)(g * DH + n0 + rr) * DH + k0 + c4 * 4];
        }
        __syncthreads();
        const int sw = ((col >> 3) & 3);
        #pragma unroll
        for (int kk4 = 0; kk4 < 16; ++kk4) {
            const int sl = (kk4 ^ sw) * 4;
            float4 w0 = *(float4*)&W[0][col][sl];
            float4 w1 = *(float4*)&W[1][col][sl];
            float4 w2 = *(float4*)&W[2][col][sl];
            float4 w3 = *(float4*)&W[3][col][sl];
            const int kk = kk4 * 4;
            #pragma unroll
            for (int j = 0; j < 4; ++j) {
                float4 av = *(float4*)&A[bq * 4 + j][kk];
                FMA4(acc[0][j], av, w0);
                FMA4(acc[1][j], av, w1);
                FMA4(acc[2][j], av, w2);
                FMA4(acc[3][j], av, w3);
            }
        }
    }

    const int hid = n0 + col;
    float w5[4][PT];
    #pragma unroll
    for (int g = 0; g < 4; ++g) {
        #pragma unroll
        for (int p = 0; p < PT; ++p) w5[g][p] = Wih[(size_t)(g * DH + hid) * 133 + p];
    }

    #pragma unroll
    for (int j = 0; j < 4; ++j) {
        const int br = bq * 4 + j;
        const int b  = b0 + br;
        float gv[4];
        #pragma unroll
        for (int g = 0; g < 4; ++g) {
            float v = acc[g][j] + Cz[(size_t)b * 2048 + g * DH + hid];
            #pragma unroll
            for (int p = 0; p < PT; ++p) v = fmaf(Xp[br][p], w5[g][p], v);
            gv[g] = v;
        }
        const size_t idx = (size_t)b * DH + hid;
        const float iv = sigf(gv[0]);
        const float fv = sigf(gv[1]);
        const float gg = tanhf(gv[2]);
        const float ov = sigf(gv[3]);
        const float cv = fv * cc[idx] + iv * gg;
        cc[idx] = cv;
        hout[idx] = ov * tanhf(cv);
    }
}

// ---------------- decoder output GEMM: Y = hc @ Wdec^T + bdec ----------------
// grid (32 batch-tiles of 16, 4 col-tiles of 32), block 256
__global__ __launch_bounds__(256) void dec_y(
    const float* __restrict__ hc, const float* __restrict__ Wdec,
    const float* __restrict__ bdec, float* __restrict__ Y)
{
    const int b0 = blockIdx.x * 16;
    const int n0 = blockIdx.y * 32;
    const int tid = threadIdx.x;
    const int col = tid & 31;
    const int bq  = tid >> 5;   // 0..7 -> 2 batches each

    __shared__ float A[16][68];
    __shared__ float W[32][68];

    float acc[2] = {};

    for (int k0 = 0; k0 < DH; k0 += 64) {
        __syncthreads();
        {
            int r = tid >> 4, c4 = tid & 15;
            *(float4*)&A[r][c4 * 4] =
                *(const float4*)&hc[(size_t)(b0 + r) * DH + k0 + c4 * 4];
        }
        #pragma unroll
        for (int l = 0; l < 2; ++l) {
            int fi = tid + l * 256;
            int r = fi >> 4, c4 = fi & 15;
            float4 wv = make_float4(0.f, 0.f, 0.f, 0.f);
            if (n0 + r < 123)
                wv = *(const float4*)&Wdec[(size_t)(n0 + r) * DH + k0 + c4 * 4];
            *(float4*)&W[r][c4 * 4] = wv;
        }
        __syncthreads();
        #pragma unroll
        for (int kk = 0; kk < 64; kk += 4) {
            float4 wv = *(float4*)&W[col][kk];
            #pragma unroll
            for (int j = 0; j < 2; ++j) {
                float4 av = *(float4*)&A[bq * 2 + j][kk];
                FMA4(acc[j], av, wv);
            }
        }
    }

    const int n = n0 + col;
    if (n < 123) {
        #pragma unroll
        for (int j = 0; j < 2; ++j)
            Y[(size_t)(b0 + bq * 2 + j) * 123 + n] = acc[j] + bdec[n];
    }
}

// ---------------- GMM sampling ----------------
// grid 4 blocks x 128 threads, one thread per batch element
__global__ __launch_bounds__(128) void sampler(
    const float* __restrict__ Y, const float* __restrict__ geps,
    const float* __restrict__ penu, float* __restrict__ out, int t)
{
    __shared__ float ylds[128 * 123];
    const int b0 = blockIdx.x * 128;
    for (int i = threadIdx.x; i < 128 * 123; i += 128)
        ylds[i] = Y[(size_t)b0 * 123 + i];
    __syncthreads();

    const int b = b0 + threadIdx.x;
    const float* y = &ylds[threadIdx.x * 123];

    float mmax = y[0];
    #pragma unroll
    for (int m = 1; m < NM; ++m) mmax = fmaxf(mmax, y[6 * m]);
    float pe[NM];
    float psum = 0.f;
    #pragma unroll
    for (int m = 0; m < NM; ++m) { pe[m] = expf(y[6 * m] - mmax); psum += pe[m]; }

    const float* ep = geps + ((size_t)t * BATCH + b) * NM * 2;
    float dx = 0.f, dy = 0.f;
    #pragma unroll
    for (int m = 0; m < NM; ++m) {
        const float pim = pe[m] / psum;
        const float mx = y[6 * m + 1], my = y[6 * m + 2];
        const float sx = expf(y[6 * m + 3]), sy = expf(y[6 * m + 4]);
        const float cor = tanhf(y[6 * m + 5]);
        const float l21 = cor / sx;
        const float l22 = sqrtf(fmaxf(sy * sy - l21 * l21, 1e-6f));
        const float e1 = ep[2 * m], e2 = ep[2 * m + 1];
        dx += pim * (mx + sx * e1);
        dy += pim * (my + fmaf(l21, e1, l22 * e2));
    }

    const float q0 = y[120], q1 = y[121], q2 = y[122];
    const float qm = fmaxf(q0, fmaxf(q1, q2));
    const float e0 = expf(q0 - qm), e1q = expf(q1 - qm), e2q = expf(q2 - qm);
    const float qs = e0 + e1q + e2q;

    const float* u = penu + ((size_t)t * BATCH + b) * 3;
    float* o = out + ((size_t)t * BATCH + b) * 5;
    o[0] = dx;
    o[1] = dy;
    o[2] = (u[0] < e0 / qs) ? 1.f : 0.f;
    o[3] = (u[1] < e1q / qs) ? 1.f : 0.f;
    o[4] = (u[2] < e2q / qs) ? 1.f : 0.f;
}

extern "C" void kernel_launch(void* const* d_in, const int* in_sizes, int n_in,
                              void* d_out, int out_size, void* d_ws, size_t ws_size,
                              hipStream_t stream)
{
    (void)in_sizes; (void)n_in; (void)out_size; (void)ws_size;

    const float* s      = (const float*)d_in[0];
    const float* WihF   = (const float*)d_in[1];
    const float* WhhF   = (const float*)d_in[2];
    const float* bF     = (const float*)d_in[3];
    const float* WihB   = (const float*)d_in[4];
    const float* WhhB   = (const float*)d_in[5];
    const float* bB     = (const float*)d_in[6];
    const float* Wmu    = (const float*)d_in[7];
    const float* bmu    = (const float*)d_in[8];
    const float* Wsig   = (const float*)d_in[9];
    const float* bsig   = (const float*)d_in[10];
    const float* Wh0    = (const float*)d_in[11];
    const float* bh0    = (const float*)d_in[12];
    const float* decWih = (const float*)d_in[13];
    const float* decWhh = (const float*)d_in[14];
    const float* decB   = (const float*)d_in[15];
    const float* Wdec   = (const float*)d_in[16];
    const float* bdec   = (const float*)d_in[17];
    const float* zeps   = (const float*)d_in[18];
    const float* geps   = (const float*)d_in[19];
    const float* penu   = (const float*)d_in[20];

    float* out = (float*)d_out;
    float* f   = (float*)d_ws;

    float* hfA = f;                 // 512*256
    float* hbA = hfA + 131072;
    float* cf  = hbA + 131072;
    float* cb  = cf  + 131072;
    float* cc  = cb  + 131072;      // 512*512
    float* hfB = cc  + 262144;
    float* hbB = hfB + 131072;
    float* hcA = hbB + 131072;      // 512*512
    float* hcB = hcA + 262144;
    float* z   = hcB + 262144;      // 512*128
    float* Cz  = z   + 65536;       // 512*2048
    float* Y   = Cz  + 1048576;     // 512*123

    // zero: hfA, hbA, cf, cb, cc
    hipMemsetAsync(f, 0, (size_t)(4 * 131072 + 262144) * sizeof(float), stream);

    for (int t = 0; t < SEQL; ++t) {
        const float* hfin = (t & 1) ? hfB : hfA;  float* hfout = (t & 1) ? hfA : hfB;
        const float* hbin = (t & 1) ? hbB : hbA;  float* hbout = (t & 1) ? hbA : hbB;
        enc_step<<<dim3(8, 16, 2), 256, 0, stream>>>(
            s, WihF, WhhF, bF, WihB, WhhB, bB,
            hfin, hfout, cf, hbin, hbout, cb, t);
    }
    // final hidden states land in hfA/hbA (t=127 writes the A buffers)
    latent_z<<<dim3(8, 4), 256, 0, stream>>>(hfA, hbA, Wmu, bmu, Wsig, bsig, zeps, z);
    gemm_small<<<dim3(8, 16), 256, 0, stream>>>(z, ZS, Wh0, ZS, 0, bh0, hcA, DH, ZS, 1);
    gemm_small<<<dim3(8, 64), 256, 0, stream>>>(z, ZS, decWih, 133, PT, decB, Cz, 2048, ZS, 0);

    for (int t = 0; t < NMAXT; ++t) {
        const float* hin = (t & 1) ? hcB : hcA;
        float* hout      = (t & 1) ? hcA : hcB;
        dec_step<<<dim3(16, 16), 256, 0, stream>>>(
            hin, hout, cc, Cz, decWhh, decWih,
            t ? (out + (size_t)(t - 1) * BATCH * 5) : nullptr, t);
        dec_y<<<dim3(32, 4), 256, 0, stream>>>(hout, Wdec, bdec, Y);
        sampler<<<dim3(4), 128, 0, stream>>>(Y, geps, penu, out, t);
    }
}